// Round 1
// baseline (284.918 us; speedup 1.0000x reference)
//
#include <hip/hip_runtime.h>
#include <hip/hip_bf16.h>
#include <stdint.h>

#define B_ROWS 8192
#define DIM 768
#define NCLS 12
#define LAM_F 0.1f
#define GAMMA_F 1.0f

typedef __bf16 bf16x8 __attribute__((ext_vector_type(8)));
typedef float f32x4 __attribute__((ext_vector_type(4)));

__device__ inline unsigned short f2bf_rne(float f) {
    union { float f; unsigned u; } v; v.f = f;
    unsigned u = v.u;
    unsigned r = (u + 0x7FFFu + ((u >> 16) & 1u)) >> 16;
    return (unsigned short)r;
}

// ---------------- Kernel 1: convert target_output -> bf16, compute row ||x||^2
__global__ __launch_bounds__(256) void prep_kernel(
    const float* __restrict__ tgt, unsigned short* __restrict__ Ebf,
    float* __restrict__ sq)
{
    int w = threadIdx.x >> 6, lane = threadIdx.x & 63;
    int row = blockIdx.x * 4 + w;
    const float4* x = (const float4*)(tgt + (size_t)row * DIM);
    float s = 0.f;
#pragma unroll
    for (int e = 0; e < 3; ++e) {
        float4 v = x[lane + 64 * e];
        s += v.x * v.x + v.y * v.y + v.z * v.z + v.w * v.w;
        ushort4 h;
        h.x = f2bf_rne(v.x); h.y = f2bf_rne(v.y);
        h.z = f2bf_rne(v.z); h.w = f2bf_rne(v.w);
        ((ushort4*)(Ebf + (size_t)row * DIM))[lane + 64 * e] = h;
    }
#pragma unroll
    for (int o = 32; o > 0; o >>= 1) s += __shfl_xor(s, o);
    if (lane == 0) sq[row] = s;
}

// ---------------- Kernel 2: logits + cross-entropy partial sum
__global__ __launch_bounds__(256) void ce_kernel(
    const float* __restrict__ pooled, const float* __restrict__ W,
    const float* __restrict__ bias, const int* __restrict__ labels,
    float* __restrict__ out /* [0]=loss, [1..]=logits */,
    float* __restrict__ cross_acc)
{
    int w = threadIdx.x >> 6, lane = threadIdx.x & 63;
    int row = blockIdx.x * 4 + w;
    const float* x = pooled + (size_t)row * DIM;
    float xr[12];
#pragma unroll
    for (int e = 0; e < 12; ++e) xr[e] = x[lane + 64 * e];
    float lg[NCLS];
#pragma unroll
    for (int c = 0; c < NCLS; ++c) {
        const float* wc = W + (size_t)c * DIM;
        float s = 0.f;
#pragma unroll
        for (int e = 0; e < 12; ++e) s += xr[e] * wc[lane + 64 * e];
#pragma unroll
        for (int o = 32; o > 0; o >>= 1) s += __shfl_xor(s, o);
        lg[c] = s + bias[c];
    }
    float* logits = out + 1;
#pragma unroll
    for (int c = 0; c < NCLS; ++c)
        if (lane == c) logits[(size_t)row * NCLS + c] = lg[c];
    if (lane == 0) {
        float mx = lg[0];
#pragma unroll
        for (int c = 1; c < NCLS; ++c) mx = fmaxf(mx, lg[c]);
        float se = 0.f;
#pragma unroll
        for (int c = 0; c < NCLS; ++c) se += expf(lg[c] - mx);
        float lse = logf(se) + mx;
        int lbl = labels[row];
        float sel = lg[0];
#pragma unroll
        for (int c = 1; c < NCLS; ++c) sel = (c == lbl) ? lg[c] : sel;
        atomicAdd(cross_acc, lse - sel);   // sum of -logp[label]
    }
}

// ---------------- Kernel 3: fused E*E^T + distance/hinge epilogue -> scalar
// Upper-triangular 128x128 tiles only; off-diagonal tiles weighted 2x.
__global__ __launch_bounds__(256) void con_kernel(
    const unsigned short* __restrict__ E, const float* __restrict__ sq,
    const int* __restrict__ lab, float* __restrict__ c_acc)
{
    __shared__ __align__(16) unsigned short As[128 * 64];
    __shared__ __align__(16) unsigned short Bs[128 * 64];

    // decode upper-tri tile index
    int p = blockIdx.x;
    int ti = 0, rem = 64;
    while (p >= rem) { p -= rem; ++ti; --rem; }
    int tj = ti + p;
    const int i0 = ti * 128, j0 = tj * 128;

    const int t = threadIdx.x;
    const int w = t >> 6, lane = t & 63;
    const int wr = w >> 1, wc = w & 1;

    f32x4 acc[4][4];
#pragma unroll
    for (int m = 0; m < 4; ++m)
#pragma unroll
        for (int n = 0; n < 4; ++n)
            acc[m][n] = (f32x4){0.f, 0.f, 0.f, 0.f};

    const int sR = w * 8 + (lane >> 3);   // staging row within a 32-row group
    const int spc = lane & 7;             // physical 16B chunk this lane fills

    for (int k0 = 0; k0 < DIM; k0 += 64) {
#pragma unroll
        for (int it = 0; it < 4; ++it) {
            int R = it * 32 + sR;
            int lc = spc ^ (R & 7);       // inverse-swizzled logical chunk
            const unsigned short* gA = E + (size_t)(i0 + R) * DIM + k0 + lc * 8;
            const unsigned short* gB = E + (size_t)(j0 + R) * DIM + k0 + lc * 8;
            __builtin_amdgcn_global_load_lds(
                (const __attribute__((address_space(1))) void*)gA,
                (__attribute__((address_space(3))) void*)(As + it * 2048 + w * 512),
                16, 0, 0);
            __builtin_amdgcn_global_load_lds(
                (const __attribute__((address_space(1))) void*)gB,
                (__attribute__((address_space(3))) void*)(Bs + it * 2048 + w * 512),
                16, 0, 0);
        }
        __syncthreads();
#pragma unroll
        for (int kk = 0; kk < 2; ++kk) {
            bf16x8 a[4], bb[4];
#pragma unroll
            for (int m = 0; m < 4; ++m) {
                int R = wr * 64 + m * 16 + (lane & 15);
                int lc = kk * 4 + (lane >> 4);
                int pc = lc ^ (R & 7);
                a[m] = *(const bf16x8*)(As + R * 64 + pc * 8);
            }
#pragma unroll
            for (int n = 0; n < 4; ++n) {
                int R = wc * 64 + n * 16 + (lane & 15);
                int lc = kk * 4 + (lane >> 4);
                int pc = lc ^ (R & 7);
                bb[n] = *(const bf16x8*)(Bs + R * 64 + pc * 8);
            }
#pragma unroll
            for (int m = 0; m < 4; ++m)
#pragma unroll
                for (int n = 0; n < 4; ++n)
                    acc[m][n] = __builtin_amdgcn_mfma_f32_16x16x32_bf16(
                        a[m], bb[n], acc[m][n], 0, 0, 0);
        }
        __syncthreads();
    }

    // epilogue: d2 = |ei|^2 + |ej|^2 - 2*dot ; same ? dist : max(0, gamma-dist)
    float lsum = 0.f;
    int jj[4]; float sqj[4]; int lbj[4];
#pragma unroll
    for (int n = 0; n < 4; ++n) {
        int j = j0 + wc * 64 + n * 16 + (lane & 15);
        jj[n] = j; sqj[n] = sq[j]; lbj[n] = lab[j];
    }
#pragma unroll
    for (int m = 0; m < 4; ++m) {
#pragma unroll
        for (int r = 0; r < 4; ++r) {
            int i = i0 + wr * 64 + m * 16 + (lane >> 4) * 4 + r;
            float sqi = sq[i]; int lbi = lab[i];
#pragma unroll
            for (int n = 0; n < 4; ++n) {
                float d2 = sqi + sqj[n] - 2.f * acc[m][n][r];
                float dist = sqrtf(fmaxf(d2, 0.f));
                float v = (lbi == lbj[n]) ? dist : fmaxf(0.f, GAMMA_F - dist);
                v = (i == jj[n]) ? 0.f : v;
                lsum += v;
            }
        }
    }
    if (ti != tj) lsum *= 2.f;
#pragma unroll
    for (int o = 32; o > 0; o >>= 1) lsum += __shfl_xor(lsum, o);
    if (lane == 0) atomicAdd(c_acc, lsum);
}

// ---------------- Kernel 4: combine
__global__ void finalize_kernel(const float* __restrict__ accs, float* __restrict__ out) {
    out[0] = (1.f - LAM_F) * (accs[0] / (float)B_ROWS) + LAM_F * accs[1];
}

extern "C" void kernel_launch(void* const* d_in, const int* in_sizes, int n_in,
                              void* d_out, int out_size, void* d_ws, size_t ws_size,
                              hipStream_t stream) {
    const float* pooled = (const float*)d_in[0];
    const float* tgt    = (const float*)d_in[1];
    const int*   labels = (const int*)d_in[2];
    const float* W      = (const float*)d_in[3];
    const float* bias   = (const float*)d_in[4];
    float* out = (float*)d_out;

    float* accs = (float*)d_ws;                              // [0]=cross, [1]=contrast
    float* sq   = (float*)((char*)d_ws + 256);               // 8192 f32
    unsigned short* Ebf = (unsigned short*)((char*)d_ws + 256 + B_ROWS * 4); // bf16 E

    hipMemsetAsync(d_ws, 0, 8, stream);
    prep_kernel<<<B_ROWS / 4, 256, 0, stream>>>(tgt, Ebf, sq);
    ce_kernel<<<B_ROWS / 4, 256, 0, stream>>>(pooled, W, bias, labels, out, accs);
    con_kernel<<<2080, 256, 0, stream>>>(Ebf, sq, labels, accs + 1);
    finalize_kernel<<<1, 1, 0, stream>>>(accs, out);
}

// Round 2
// 194.830 us; speedup vs baseline: 1.4624x; 1.4624x over previous
//
#include <hip/hip_runtime.h>
#include <hip/hip_bf16.h>
#include <stdint.h>

#define B_ROWS 8192
#define DIM 768
#define NCLS 12
#define LAM_F 0.1f
#define GAMMA_F 1.0f
#define NTILE 64          // 8192/128
#define NBLK_CON 2080     // NTILE*(NTILE+1)/2
#define NBLK_CE 2048

typedef __bf16 bf16x8 __attribute__((ext_vector_type(8)));
typedef float f32x4 __attribute__((ext_vector_type(4)));

__device__ inline unsigned short f2bf_rne(float f) {
    union { float f; unsigned u; } v; v.f = f;
    unsigned u = v.u;
    unsigned r = (u + 0x7FFFu + ((u >> 16) & 1u)) >> 16;
    return (unsigned short)r;
}

// ---------------- Kernel 1: convert target_output -> bf16, compute row ||x||^2
__global__ __launch_bounds__(256) void prep_kernel(
    const float* __restrict__ tgt, unsigned short* __restrict__ Ebf,
    float* __restrict__ sq)
{
    int w = threadIdx.x >> 6, lane = threadIdx.x & 63;
    int row = blockIdx.x * 4 + w;
    const float4* x = (const float4*)(tgt + (size_t)row * DIM);
    float s = 0.f;
#pragma unroll
    for (int e = 0; e < 3; ++e) {
        float4 v = x[lane + 64 * e];
        s += v.x * v.x + v.y * v.y + v.z * v.z + v.w * v.w;
        ushort4 h;
        h.x = f2bf_rne(v.x); h.y = f2bf_rne(v.y);
        h.z = f2bf_rne(v.z); h.w = f2bf_rne(v.w);
        ((ushort4*)(Ebf + (size_t)row * DIM))[lane + 64 * e] = h;
    }
#pragma unroll
    for (int o = 32; o > 0; o >>= 1) s += __shfl_xor(s, o);
    if (lane == 0) sq[row] = s;
}

// ---------------- Kernel 2: logits + cross-entropy per-block partial (NO atomics)
__global__ __launch_bounds__(256) void ce_kernel(
    const float* __restrict__ pooled, const float* __restrict__ W,
    const float* __restrict__ bias, const int* __restrict__ labels,
    float* __restrict__ out /* [0]=loss, [1..]=logits */,
    float* __restrict__ csum)
{
    __shared__ float red[4];
    int w = threadIdx.x >> 6, lane = threadIdx.x & 63;
    int row = blockIdx.x * 4 + w;
    const float4* x = (const float4*)(pooled + (size_t)row * DIM);
    float4 xr[3];
#pragma unroll
    for (int e = 0; e < 3; ++e) xr[e] = x[lane + 64 * e];
    float lg[NCLS];
#pragma unroll
    for (int c = 0; c < NCLS; ++c) {
        const float4* wc = (const float4*)(W + (size_t)c * DIM);
        float s = 0.f;
#pragma unroll
        for (int e = 0; e < 3; ++e) {
            float4 wv = wc[lane + 64 * e];
            s += xr[e].x * wv.x + xr[e].y * wv.y + xr[e].z * wv.z + xr[e].w * wv.w;
        }
#pragma unroll
        for (int o = 32; o > 0; o >>= 1) s += __shfl_xor(s, o);
        lg[c] = s + bias[c];
    }
    float* logits = out + 1;
#pragma unroll
    for (int c = 0; c < NCLS; ++c)
        if (lane == c) logits[(size_t)row * NCLS + c] = lg[c];
    if (lane == 0) {
        float mx = lg[0];
#pragma unroll
        for (int c = 1; c < NCLS; ++c) mx = fmaxf(mx, lg[c]);
        float se = 0.f;
#pragma unroll
        for (int c = 0; c < NCLS; ++c) se += expf(lg[c] - mx);
        float lse = logf(se) + mx;
        int lbl = labels[row];
        float sel = lg[0];
#pragma unroll
        for (int c = 1; c < NCLS; ++c) sel = (c == lbl) ? lg[c] : sel;
        red[w] = lse - sel;
    }
    __syncthreads();
    if (threadIdx.x == 0) csum[blockIdx.x] = red[0] + red[1] + red[2] + red[3];
}

// ---------------- Kernel 3: fused E*E^T + distance/hinge, 2-phase double-buffered
// Upper-triangular 128x128 tiles; off-diagonal weighted 2x; per-block partial out.
#define CON_STAGE(buf, k0)                                                         \
    {                                                                              \
        _Pragma("unroll")                                                          \
        for (int it = 0; it < 4; ++it) {                                           \
            int R = it * 32 + sR;                                                  \
            int lc = spc ^ (R & 7);                                                \
            const unsigned short* gA = E + (size_t)(i0 + R) * DIM + (k0) + lc * 8; \
            const unsigned short* gB = E + (size_t)(j0 + R) * DIM + (k0) + lc * 8; \
            __builtin_amdgcn_global_load_lds(                                      \
                (const __attribute__((address_space(1))) void*)gA,                 \
                (__attribute__((address_space(3))) void*)(&As[buf][it * 2048 + w * 512]), \
                16, 0, 0);                                                         \
            __builtin_amdgcn_global_load_lds(                                      \
                (const __attribute__((address_space(1))) void*)gB,                 \
                (__attribute__((address_space(3))) void*)(&Bs[buf][it * 2048 + w * 512]), \
                16, 0, 0);                                                         \
        }                                                                          \
    }

#define CON_COMPUTE(buf)                                                           \
    {                                                                              \
        _Pragma("unroll")                                                          \
        for (int kk = 0; kk < 2; ++kk) {                                           \
            bf16x8 a[4], bb[4];                                                    \
            _Pragma("unroll")                                                      \
            for (int m = 0; m < 4; ++m) {                                          \
                int R = wr * 64 + m * 16 + (lane & 15);                            \
                int lc = kk * 4 + (lane >> 4);                                     \
                int pc = lc ^ (R & 7);                                             \
                a[m] = *(const bf16x8*)(&As[buf][R * 64 + pc * 8]);                \
            }                                                                      \
            _Pragma("unroll")                                                      \
            for (int n = 0; n < 4; ++n) {                                          \
                int R = wc * 64 + n * 16 + (lane & 15);                            \
                int lc = kk * 4 + (lane >> 4);                                     \
                int pc = lc ^ (R & 7);                                             \
                bb[n] = *(const bf16x8*)(&Bs[buf][R * 64 + pc * 8]);               \
            }                                                                      \
            _Pragma("unroll")                                                      \
            for (int m = 0; m < 4; ++m)                                            \
                _Pragma("unroll")                                                  \
                for (int n = 0; n < 4; ++n)                                        \
                    acc[m][n] = __builtin_amdgcn_mfma_f32_16x16x32_bf16(           \
                        a[m], bb[n], acc[m][n], 0, 0, 0);                          \
        }                                                                          \
    }

__global__ __launch_bounds__(256) void con_kernel(
    const unsigned short* __restrict__ E, const float* __restrict__ sq,
    const int* __restrict__ lab, float* __restrict__ psum)
{
    __shared__ __align__(16) unsigned short As[2][128 * 64];
    __shared__ __align__(16) unsigned short Bs[2][128 * 64];
    __shared__ float red[4];

    // decode upper-tri tile index
    int p = blockIdx.x;
    int ti = 0, rem = NTILE;
    while (p >= rem) { p -= rem; ++ti; --rem; }
    int tj = ti + p;
    const int i0 = ti * 128, j0 = tj * 128;

    const int t = threadIdx.x;
    const int w = t >> 6, lane = t & 63;
    const int wr = w >> 1, wc = w & 1;

    f32x4 acc[4][4];
#pragma unroll
    for (int m = 0; m < 4; ++m)
#pragma unroll
        for (int n = 0; n < 4; ++n)
            acc[m][n] = (f32x4){0.f, 0.f, 0.f, 0.f};

    const int sR = w * 8 + (lane >> 3);   // staging row within a 32-row group
    const int spc = lane & 7;             // physical 16B chunk this lane fills

    // prologue
    CON_STAGE(0, 0);
    __syncthreads();
    int cur = 0;
#pragma unroll 1
    for (int ks = 0; ks < (DIM / 64) - 1; ++ks) {
        CON_STAGE(cur ^ 1, (ks + 1) * 64);   // prefetch next tile
        CON_COMPUTE(cur);                    // compute current
        __syncthreads();                     // drains vmcnt(0)+lgkmcnt(0)
        cur ^= 1;
    }
    CON_COMPUTE(cur);                        // last tile, already staged

    // epilogue: d2 = |ei|^2 + |ej|^2 - 2*dot ; same ? dist : max(0, gamma-dist)
    float lsum = 0.f;
    int jj[4]; float sqj[4]; int lbj[4];
#pragma unroll
    for (int n = 0; n < 4; ++n) {
        int j = j0 + wc * 64 + n * 16 + (lane & 15);
        jj[n] = j; sqj[n] = sq[j]; lbj[n] = lab[j];
    }
#pragma unroll
    for (int m = 0; m < 4; ++m) {
#pragma unroll
        for (int r = 0; r < 4; ++r) {
            int i = i0 + wr * 64 + m * 16 + (lane >> 4) * 4 + r;
            float sqi = sq[i]; int lbi = lab[i];
#pragma unroll
            for (int n = 0; n < 4; ++n) {
                float d2 = sqi + sqj[n] - 2.f * acc[m][n][r];
                float dist = sqrtf(fmaxf(d2, 0.f));
                float v = (lbi == lbj[n]) ? dist : fmaxf(0.f, GAMMA_F - dist);
                v = (i == jj[n]) ? 0.f : v;
                lsum += v;
            }
        }
    }
    if (ti != tj) lsum *= 2.f;
#pragma unroll
    for (int o = 32; o > 0; o >>= 1) lsum += __shfl_xor(lsum, o);
    if (lane == 0) red[w] = lsum;
    __syncthreads();
    if (t == 0) psum[blockIdx.x] = red[0] + red[1] + red[2] + red[3];
}

// ---------------- Kernel 4: tree-reduce partials + combine
__global__ __launch_bounds__(256) void finalize_kernel(
    const float* __restrict__ csum, const float* __restrict__ psum,
    float* __restrict__ out)
{
    __shared__ float rce[4], rcon[4];
    int w = threadIdx.x >> 6, lane = threadIdx.x & 63;
    float s_ce = 0.f, s_con = 0.f;
    for (int i = threadIdx.x; i < NBLK_CE; i += 256) s_ce += csum[i];
    for (int i = threadIdx.x; i < NBLK_CON; i += 256) s_con += psum[i];
#pragma unroll
    for (int o = 32; o > 0; o >>= 1) {
        s_ce += __shfl_xor(s_ce, o);
        s_con += __shfl_xor(s_con, o);
    }
    if (lane == 0) { rce[w] = s_ce; rcon[w] = s_con; }
    __syncthreads();
    if (threadIdx.x == 0) {
        float ce = rce[0] + rce[1] + rce[2] + rce[3];
        float con = rcon[0] + rcon[1] + rcon[2] + rcon[3];
        out[0] = (1.f - LAM_F) * (ce / (float)B_ROWS) + LAM_F * con;
    }
}

extern "C" void kernel_launch(void* const* d_in, const int* in_sizes, int n_in,
                              void* d_out, int out_size, void* d_ws, size_t ws_size,
                              hipStream_t stream) {
    const float* pooled = (const float*)d_in[0];
    const float* tgt    = (const float*)d_in[1];
    const int*   labels = (const int*)d_in[2];
    const float* W      = (const float*)d_in[3];
    const float* bias   = (const float*)d_in[4];
    float* out = (float*)d_out;

    float* csum = (float*)d_ws;                                   // 2048 f32
    float* psum = (float*)((char*)d_ws + 8192);                   // 2080 f32
    float* sq   = (float*)((char*)d_ws + 20480);                  // 8192 f32
    unsigned short* Ebf = (unsigned short*)((char*)d_ws + 53248); // bf16 E, 12.6 MB

    prep_kernel<<<B_ROWS / 4, 256, 0, stream>>>(tgt, Ebf, sq);
    ce_kernel<<<NBLK_CE, 256, 0, stream>>>(pooled, W, bias, labels, out, csum);
    con_kernel<<<NBLK_CON, 256, 0, stream>>>(Ebf, sq, labels, psum);
    finalize_kernel<<<1, 256, 0, stream>>>(csum, psum, out);
}

// Round 3
// 152.206 us; speedup vs baseline: 1.8719x; 1.2800x over previous
//
#include <hip/hip_runtime.h>
#include <hip/hip_bf16.h>
#include <stdint.h>

#define B_ROWS 8192
#define DIM 768
#define NCLS 12
#define LAM_F 0.1f
#define GAMMA_F 1.0f
#define NTILE2 32          // 8192/256
#define NBLK_CON 528       // 32*33/2
#define NBLK_CE 2048
#define NKT 12             // 768/64 K-tiles

typedef __bf16 bf16x8 __attribute__((ext_vector_type(8)));
typedef float f32x4 __attribute__((ext_vector_type(4)));

__device__ inline unsigned short f2bf_rne(float f) {
    union { float f; unsigned u; } v; v.f = f;
    unsigned u = v.u;
    unsigned r = (u + 0x7FFFu + ((u >> 16) & 1u)) >> 16;
    return (unsigned short)r;
}

// ---------------- Kernel 1: convert target_output -> bf16, compute row ||x||^2
__global__ __launch_bounds__(256) void prep_kernel(
    const float* __restrict__ tgt, unsigned short* __restrict__ Ebf,
    float* __restrict__ sq)
{
    int w = threadIdx.x >> 6, lane = threadIdx.x & 63;
    int row = blockIdx.x * 4 + w;
    const float4* x = (const float4*)(tgt + (size_t)row * DIM);
    float s = 0.f;
#pragma unroll
    for (int e = 0; e < 3; ++e) {
        float4 v = x[lane + 64 * e];
        s += v.x * v.x + v.y * v.y + v.z * v.z + v.w * v.w;
        ushort4 h;
        h.x = f2bf_rne(v.x); h.y = f2bf_rne(v.y);
        h.z = f2bf_rne(v.z); h.w = f2bf_rne(v.w);
        ((ushort4*)(Ebf + (size_t)row * DIM))[lane + 64 * e] = h;
    }
#pragma unroll
    for (int o = 32; o > 0; o >>= 1) s += __shfl_xor(s, o);
    if (lane == 0) sq[row] = s;
}

// ---------------- Kernel 2: logits + cross-entropy per-block partial (NO atomics)
__global__ __launch_bounds__(256) void ce_kernel(
    const float* __restrict__ pooled, const float* __restrict__ W,
    const float* __restrict__ bias, const int* __restrict__ labels,
    float* __restrict__ out /* [0]=loss, [1..]=logits */,
    float* __restrict__ csum)
{
    __shared__ float red[4];
    int w = threadIdx.x >> 6, lane = threadIdx.x & 63;
    int row = blockIdx.x * 4 + w;
    const float4* x = (const float4*)(pooled + (size_t)row * DIM);
    float4 xr[3];
#pragma unroll
    for (int e = 0; e < 3; ++e) xr[e] = x[lane + 64 * e];
    float lg[NCLS];
#pragma unroll
    for (int c = 0; c < NCLS; ++c) {
        const float4* wc = (const float4*)(W + (size_t)c * DIM);
        float s = 0.f;
#pragma unroll
        for (int e = 0; e < 3; ++e) {
            float4 wv = wc[lane + 64 * e];
            s += xr[e].x * wv.x + xr[e].y * wv.y + xr[e].z * wv.z + xr[e].w * wv.w;
        }
#pragma unroll
        for (int o = 32; o > 0; o >>= 1) s += __shfl_xor(s, o);
        lg[c] = s + bias[c];
    }
    float* logits = out + 1;
#pragma unroll
    for (int c = 0; c < NCLS; ++c)
        if (lane == c) logits[(size_t)row * NCLS + c] = lg[c];
    if (lane == 0) {
        float mx = lg[0];
#pragma unroll
        for (int c = 1; c < NCLS; ++c) mx = fmaxf(mx, lg[c]);
        float se = 0.f;
#pragma unroll
        for (int c = 0; c < NCLS; ++c) se += expf(lg[c] - mx);
        float lse = logf(se) + mx;
        int lbl = labels[row];
        float sel = lg[0];
#pragma unroll
        for (int c = 1; c < NCLS; ++c) sel = (c == lbl) ? lg[c] : sel;
        red[w] = lse - sel;
    }
    __syncthreads();
    if (threadIdx.x == 0) csum[blockIdx.x] = red[0] + red[1] + red[2] + red[3];
}

// ---------------- Kernel 3: 256^2 8-phase E*E^T + hinge epilogue
// Slots: As/Bs[dbuf][khalf] = 256 rows x 32 cols bf16 = 16 KB each (128 KiB total).
// Per K-tile: 4 phases (kk,nh). Stage schedule (tile t, parity d):
//   p0 stages B_{t+1}[kh1] -> Bs[d^1][1]   (slot last read p3 of t-1)
//   p1 stages A_{t+2}[kh0] -> As[d][0]     (slot last read p0 of t)
//   p2 stages B_{t+2}[kh0] -> Bs[d][0]     (slot last read p1 of t)
//   p3 stages A_{t+2}[kh1] -> As[d][1]     (slot last read p2 of t)
// vmcnt(6) once per tile at end of p3 => tile t+1 fully staged, 3 half-slots
// (tile t+2 partial) stay in flight. Tail tiles stage wrapped (dead) addresses
// to keep counts uniform.

#define STAGE_SLOT(slotPtr, row0, kt, kh)                                         \
    { _Pragma("unroll")                                                           \
      for (int l = 0; l < 2; ++l) {                                               \
          int R_ = l * 128 + w * 16 + (lane >> 2);                                \
          int lc_ = (lane & 3) ^ (R_ & 3);                                        \
          const unsigned short* g_ = E + (size_t)((row0) + R_) * DIM              \
                                       + (kt) * 64 + (kh) * 32 + lc_ * 8;         \
          __builtin_amdgcn_global_load_lds(                                       \
              (const __attribute__((address_space(1))) void*)g_,                  \
              (__attribute__((address_space(3))) void*)((slotPtr) + l * 4096 + w * 512), \
              16, 0, 0);                                                          \
      } }

#define LOAD_A(d, kk)                                                             \
    { _Pragma("unroll")                                                           \
      for (int m_ = 0; m_ < 8; ++m_) {                                            \
          int R_ = wr * 128 + m_ * 16 + (lane & 15);                              \
          int pc_ = (lane >> 4) ^ (R_ & 3);                                       \
          af[m_] = *(const bf16x8*)(&As[d][kk][R_ * 32 + pc_ * 8]);               \
      } }

#define LOAD_B2(d, kk, n0)                                                        \
    { _Pragma("unroll")                                                           \
      for (int q_ = 0; q_ < 2; ++q_) {                                            \
          int R_ = wc * 64 + ((n0) + q_) * 16 + (lane & 15);                      \
          int pc_ = (lane >> 4) ^ (R_ & 3);                                       \
          bf[(n0) + q_] = *(const bf16x8*)(&Bs[d][kk][R_ * 32 + pc_ * 8]);        \
      } }

#define MFMA_NH(nh)                                                               \
    {   __builtin_amdgcn_s_barrier();                                             \
        __builtin_amdgcn_sched_barrier(0);                                        \
        __builtin_amdgcn_s_setprio(1);                                            \
        _Pragma("unroll")                                                         \
        for (int m_ = 0; m_ < 8; ++m_) {                                          \
            acc[m_][(nh)*2]   = __builtin_amdgcn_mfma_f32_16x16x32_bf16(          \
                af[m_], bf[(nh)*2],   acc[m_][(nh)*2],   0, 0, 0);                \
            acc[m_][(nh)*2+1] = __builtin_amdgcn_mfma_f32_16x16x32_bf16(          \
                af[m_], bf[(nh)*2+1], acc[m_][(nh)*2+1], 0, 0, 0);                \
        }                                                                         \
        __builtin_amdgcn_s_setprio(0);                                            \
        __builtin_amdgcn_sched_barrier(0);                                        \
    }

#define END_BARRIER                                                               \
    {   __builtin_amdgcn_s_barrier();                                             \
        asm volatile("" ::: "memory");                                            \
    }

__global__ __launch_bounds__(512, 2) void con_kernel(
    const unsigned short* __restrict__ E, const float* __restrict__ sq,
    const int* __restrict__ lab, float* __restrict__ psum)
{
    __shared__ __align__(16) unsigned short As[2][2][8192];
    __shared__ __align__(16) unsigned short Bs[2][2][8192];
    __shared__ float red[8];

    // bijective XCD swizzle (528 % 8 == 0), then upper-tri decode
    int bid = blockIdx.x;
    int swz = (bid & 7) * (NBLK_CON / 8) + (bid >> 3);
    int p = swz;
    int ti = 0, rem = NTILE2;
    while (p >= rem) { p -= rem; ++ti; --rem; }
    int tj = ti + p;
    const int i0 = ti * 256, j0 = tj * 256;

    const int t = threadIdx.x;
    const int w = t >> 6, lane = t & 63;
    const int wr = w >> 2, wc = w & 3;   // 2M x 4N waves; per-wave out 128x64

    f32x4 acc[8][4];
#pragma unroll
    for (int m = 0; m < 8; ++m)
#pragma unroll
        for (int n = 0; n < 4; ++n)
            acc[m][n] = (f32x4){0.f, 0.f, 0.f, 0.f};

    bf16x8 af[8], bf[4];

    // ---- prologue: tile0 all 4 slots + tile1 first 3 slots
    STAGE_SLOT(&As[0][0][0], i0, 0, 0);
    STAGE_SLOT(&Bs[0][0][0], j0, 0, 0);
    STAGE_SLOT(&As[0][1][0], i0, 0, 1);
    STAGE_SLOT(&Bs[0][1][0], j0, 0, 1);
    STAGE_SLOT(&As[1][0][0], i0, 1, 0);
    STAGE_SLOT(&Bs[1][0][0], j0, 1, 0);
    STAGE_SLOT(&As[1][1][0], i0, 1, 1);
    asm volatile("s_waitcnt vmcnt(6)" ::: "memory");
    END_BARRIER;

    // ---- main loop: 12 K-tiles, 4 phases each
#pragma unroll 1
    for (int kt = 0; kt < NKT; ++kt) {
        const int d = kt & 1;
        const int kt1 = (kt + 1 < NKT) ? kt + 1 : kt + 1 - NKT;
        const int kt2 = (kt + 2 < NKT) ? kt + 2 : kt + 2 - NKT;

        // p0: (kk=0, nh=0)
        LOAD_A(d, 0);
        LOAD_B2(d, 0, 0);
        STAGE_SLOT(&Bs[d ^ 1][1][0], j0, kt1, 1);
        MFMA_NH(0);
        END_BARRIER;

        // p1: (kk=0, nh=1)
        LOAD_B2(d, 0, 2);
        STAGE_SLOT(&As[d][0][0], i0, kt2, 0);
        MFMA_NH(1);
        END_BARRIER;

        // p2: (kk=1, nh=0)
        LOAD_A(d, 1);
        LOAD_B2(d, 1, 0);
        STAGE_SLOT(&Bs[d][0][0], j0, kt2, 0);
        MFMA_NH(0);
        END_BARRIER;

        // p3: (kk=1, nh=1)
        LOAD_B2(d, 1, 2);
        STAGE_SLOT(&As[d][1][0], i0, kt2, 1);
        MFMA_NH(1);
        asm volatile("s_waitcnt vmcnt(6)" ::: "memory");
        END_BARRIER;
    }

    // ---- epilogue: d2 = |ei|^2+|ej|^2-2*dot ; same ? dist : max(0, gamma-dist)
    float lsum = 0.f;
    int jj[4]; float sqj[4]; int lbj[4];
#pragma unroll
    for (int n = 0; n < 4; ++n) {
        int j = j0 + wc * 64 + n * 16 + (lane & 15);
        jj[n] = j; sqj[n] = sq[j]; lbj[n] = lab[j];
    }
#pragma unroll
    for (int m = 0; m < 8; ++m) {
#pragma unroll
        for (int r = 0; r < 4; ++r) {
            int i = i0 + wr * 128 + m * 16 + (lane >> 4) * 4 + r;
            float sqi = sq[i]; int lbi = lab[i];
#pragma unroll
            for (int n = 0; n < 4; ++n) {
                float d2 = sqi + sqj[n] - 2.f * acc[m][n][r];
                float dist = sqrtf(fmaxf(d2, 0.f));
                float v = (lbi == lbj[n]) ? dist : fmaxf(0.f, GAMMA_F - dist);
                v = (i == jj[n]) ? 0.f : v;
                lsum += v;
            }
        }
    }
    if (ti != tj) lsum *= 2.f;
#pragma unroll
    for (int o = 32; o > 0; o >>= 1) lsum += __shfl_xor(lsum, o);
    if (lane == 0) red[w] = lsum;
    __syncthreads();
    if (t == 0) {
        float s = 0.f;
#pragma unroll
        for (int q = 0; q < 8; ++q) s += red[q];
        psum[blockIdx.x] = s;
    }
}

// ---------------- Kernel 4: tree-reduce partials + combine
__global__ __launch_bounds__(256) void finalize_kernel(
    const float* __restrict__ csum, const float* __restrict__ psum,
    float* __restrict__ out)
{
    __shared__ float rce[4], rcon[4];
    int w = threadIdx.x >> 6, lane = threadIdx.x & 63;
    float s_ce = 0.f, s_con = 0.f;
    for (int i = threadIdx.x; i < NBLK_CE; i += 256) s_ce += csum[i];
    for (int i = threadIdx.x; i < NBLK_CON; i += 256) s_con += psum[i];
#pragma unroll
    for (int o = 32; o > 0; o >>= 1) {
        s_ce += __shfl_xor(s_ce, o);
        s_con += __shfl_xor(s_con, o);
    }
    if (lane == 0) { rce[w] = s_ce; rcon[w] = s_con; }
    __syncthreads();
    if (threadIdx.x == 0) {
        float ce = rce[0] + rce[1] + rce[2] + rce[3];
        float con = rcon[0] + rcon[1] + rcon[2] + rcon[3];
        out[0] = (1.f - LAM_F) * (ce / (float)B_ROWS) + LAM_F * con;
    }
}

extern "C" void kernel_launch(void* const* d_in, const int* in_sizes, int n_in,
                              void* d_out, int out_size, void* d_ws, size_t ws_size,
                              hipStream_t stream) {
    const float* pooled = (const float*)d_in[0];
    const float* tgt    = (const float*)d_in[1];
    const int*   labels = (const int*)d_in[2];
    const float* W      = (const float*)d_in[3];
    const float* bias   = (const float*)d_in[4];
    float* out = (float*)d_out;

    float* csum = (float*)d_ws;                                   // 2048 f32
    float* psum = (float*)((char*)d_ws + 8192);                   // 528 f32
    float* sq   = (float*)((char*)d_ws + 20480);                  // 8192 f32
    unsigned short* Ebf = (unsigned short*)((char*)d_ws + 53248); // bf16 E, 12.6 MB

    prep_kernel<<<B_ROWS / 4, 256, 0, stream>>>(tgt, Ebf, sq);
    ce_kernel<<<NBLK_CE, 256, 0, stream>>>(pooled, W, bias, labels, out, csum);
    con_kernel<<<NBLK_CON, 512, 0, stream>>>(Ebf, sq, labels, psum);
    finalize_kernel<<<1, 256, 0, stream>>>(csum, psum, out);
}

// Round 4
// 118.113 us; speedup vs baseline: 2.4122x; 1.2887x over previous
//
#include <hip/hip_runtime.h>
#include <hip/hip_bf16.h>
#include <stdint.h>

#define B_ROWS 8192
#define DIM 768
#define NCLS 12
#define LAM_F 0.1f
#define GAMMA_F 1.0f
#define NBLK_CON 1056      // #{(ti,tj): ti<32, tj<64, tj>=2ti} = sum(64-2ti) = 1056
#define NBLK_CE 2048
#define NKS 24             // 768/32 K-steps

typedef __bf16 bf16x8 __attribute__((ext_vector_type(8)));
typedef float f32x4 __attribute__((ext_vector_type(4)));

__device__ inline unsigned short f2bf_rne(float f) {
    union { float f; unsigned u; } v; v.f = f;
    unsigned u = v.u;
    unsigned r = (u + 0x7FFFu + ((u >> 16) & 1u)) >> 16;
    return (unsigned short)r;
}

// ---------------- Kernel 1: convert target_output -> bf16, compute row ||x||^2
__global__ __launch_bounds__(256) void prep_kernel(
    const float* __restrict__ tgt, unsigned short* __restrict__ Ebf,
    float* __restrict__ sq)
{
    int w = threadIdx.x >> 6, lane = threadIdx.x & 63;
    int row = blockIdx.x * 4 + w;
    const float4* x = (const float4*)(tgt + (size_t)row * DIM);
    float s = 0.f;
#pragma unroll
    for (int e = 0; e < 3; ++e) {
        float4 v = x[lane + 64 * e];
        s += v.x * v.x + v.y * v.y + v.z * v.z + v.w * v.w;
        ushort4 h;
        h.x = f2bf_rne(v.x); h.y = f2bf_rne(v.y);
        h.z = f2bf_rne(v.z); h.w = f2bf_rne(v.w);
        ((ushort4*)(Ebf + (size_t)row * DIM))[lane + 64 * e] = h;
    }
#pragma unroll
    for (int o = 32; o > 0; o >>= 1) s += __shfl_xor(s, o);
    if (lane == 0) sq[row] = s;
}

// ---------------- Kernel 2: logits + cross-entropy per-block partial (NO atomics)
__global__ __launch_bounds__(256) void ce_kernel(
    const float* __restrict__ pooled, const float* __restrict__ W,
    const float* __restrict__ bias, const int* __restrict__ labels,
    float* __restrict__ out /* [0]=loss, [1..]=logits */,
    float* __restrict__ csum)
{
    __shared__ float red[4];
    int w = threadIdx.x >> 6, lane = threadIdx.x & 63;
    int row = blockIdx.x * 4 + w;
    const float4* x = (const float4*)(pooled + (size_t)row * DIM);
    float4 xr[3];
#pragma unroll
    for (int e = 0; e < 3; ++e) xr[e] = x[lane + 64 * e];
    float lg[NCLS];
#pragma unroll
    for (int c = 0; c < NCLS; ++c) {
        const float4* wc = (const float4*)(W + (size_t)c * DIM);
        float s = 0.f;
#pragma unroll
        for (int e = 0; e < 3; ++e) {
            float4 wv = wc[lane + 64 * e];
            s += xr[e].x * wv.x + xr[e].y * wv.y + xr[e].z * wv.z + xr[e].w * wv.w;
        }
#pragma unroll
        for (int o = 32; o > 0; o >>= 1) s += __shfl_xor(s, o);
        lg[c] = s + bias[c];
    }
    float* logits = out + 1;
#pragma unroll
    for (int c = 0; c < NCLS; ++c)
        if (lane == c) logits[(size_t)row * NCLS + c] = lg[c];
    if (lane == 0) {
        float mx = lg[0];
#pragma unroll
        for (int c = 1; c < NCLS; ++c) mx = fmaxf(mx, lg[c]);
        float se = 0.f;
#pragma unroll
        for (int c = 0; c < NCLS; ++c) se += expf(lg[c] - mx);
        float lse = logf(se) + mx;
        int lbl = labels[row];
        float sel = lg[0];
#pragma unroll
        for (int c = 1; c < NCLS; ++c) sel = (c == lbl) ? lg[c] : sel;
        red[w] = lse - sel;
    }
    __syncthreads();
    if (threadIdx.x == 0) csum[blockIdx.x] = red[0] + red[1] + red[2] + red[3];
}

// ---------------- Kernel 3: 256x128-tile E*E^T + hinge epilogue, BK=32 dbuf,
// m97-style 2-phase (STAGE next / COMPUTE cur / __syncthreads drain).
// 8 waves as 4x2, per-wave 64x64 out (acc = 64 AGPR). launch_bounds(512,4)
// caps regs at 128/wave -> 2 blocks/CU. Strict i<j mask, weight 2.
// LDS row = 32 bf16 = 64B; conflict-free involution: chunk ^= (row>>1)&3.

#define STAGE_STEP(d, ks)                                                        \
    { const int k0_ = (ks) * 32;                                                 \
      _Pragma("unroll")                                                          \
      for (int l = 0; l < 2; ++l) {                                              \
          int R_ = l * 128 + w * 16 + (lane >> 2);                               \
          int lc_ = (lane & 3) ^ ((R_ >> 1) & 3);                                \
          const unsigned short* g_ = E + (size_t)(i0 + R_) * DIM + k0_ + lc_ * 8;\
          __builtin_amdgcn_global_load_lds(                                      \
              (const __attribute__((address_space(1))) void*)g_,                 \
              (__attribute__((address_space(3))) void*)(&As[d][l * 4096 + w * 512]), \
              16, 0, 0);                                                         \
      }                                                                          \
      { int R_ = w * 16 + (lane >> 2);                                           \
        int lc_ = (lane & 3) ^ ((R_ >> 1) & 3);                                  \
        const unsigned short* g_ = E + (size_t)(j0 + R_) * DIM + k0_ + lc_ * 8;  \
        __builtin_amdgcn_global_load_lds(                                        \
            (const __attribute__((address_space(1))) void*)g_,                   \
            (__attribute__((address_space(3))) void*)(&Bs[d][w * 512]),          \
            16, 0, 0);                                                           \
      } }

#define COMPUTE_STEP(d)                                                          \
    { bf16x8 af[4], bf[4];                                                       \
      _Pragma("unroll")                                                          \
      for (int m_ = 0; m_ < 4; ++m_) {                                           \
          int R_ = wr * 64 + m_ * 16 + (lane & 15);                              \
          int pc_ = (lane >> 4) ^ ((R_ >> 1) & 3);                               \
          af[m_] = *(const bf16x8*)(&As[d][R_ * 32 + pc_ * 8]);                  \
      }                                                                          \
      _Pragma("unroll")                                                          \
      for (int n_ = 0; n_ < 4; ++n_) {                                           \
          int R_ = wc * 64 + n_ * 16 + (lane & 15);                              \
          int pc_ = (lane >> 4) ^ ((R_ >> 1) & 3);                               \
          bf[n_] = *(const bf16x8*)(&Bs[d][R_ * 32 + pc_ * 8]);                  \
      }                                                                          \
      _Pragma("unroll")                                                          \
      for (int m_ = 0; m_ < 4; ++m_)                                             \
          _Pragma("unroll")                                                      \
          for (int n_ = 0; n_ < 4; ++n_)                                         \
              acc[m_][n_] = __builtin_amdgcn_mfma_f32_16x16x32_bf16(             \
                  af[m_], bf[n_], acc[m_][n_], 0, 0, 0);                         \
    }

__global__ __launch_bounds__(512, 4) void con_kernel(
    const unsigned short* __restrict__ E, const float* __restrict__ sq,
    const int* __restrict__ lab, float* __restrict__ psum)
{
    __shared__ __align__(16) unsigned short As[2][8192];  // 256 x 32 bf16 per buf
    __shared__ __align__(16) unsigned short Bs[2][4096];  // 128 x 32 bf16 per buf
    __shared__ float red[8];

    // bijective XCD swizzle (1056 = 8*132), then wedge decode (tj >= 2*ti)
    int bid = blockIdx.x;
    int swz = (bid & 7) * (NBLK_CON / 8) + (bid >> 3);
    int p = swz;
    int ti = 0, rem = 64;
    while (p >= rem) { p -= rem; ++ti; rem -= 2; }
    int tj = 2 * ti + p;
    const int i0 = ti * 256, j0 = tj * 128;

    const int t = threadIdx.x;
    const int w = t >> 6, lane = t & 63;
    const int wr = w >> 1, wc = w & 1;   // 4M x 2N waves; per-wave out 64x64

    f32x4 acc[4][4];
#pragma unroll
    for (int m = 0; m < 4; ++m)
#pragma unroll
        for (int n = 0; n < 4; ++n)
            acc[m][n] = (f32x4){0.f, 0.f, 0.f, 0.f};

    // prologue
    STAGE_STEP(0, 0);
    __syncthreads();
#pragma unroll 1
    for (int ks = 0; ks < NKS - 1; ++ks) {
        STAGE_STEP((ks & 1) ^ 1, ks + 1);   // issue next-step loads first
        COMPUTE_STEP(ks & 1);               // ds_read + 16 MFMA overlap the flight
        __syncthreads();                    // drains vmcnt(0)+lgkmcnt(0)
    }
    COMPUTE_STEP((NKS - 1) & 1);

    // epilogue: d2 = |ei|^2+|ej|^2-2*dot ; same ? dist : max(0, gamma-dist)
    // strict upper mask i<j (weight 2 applied at psum write)
    float lsum = 0.f;
    int jj[4]; float sqj[4]; int lbj[4];
#pragma unroll
    for (int n = 0; n < 4; ++n) {
        int j = j0 + wc * 64 + n * 16 + (lane & 15);
        jj[n] = j; sqj[n] = sq[j]; lbj[n] = lab[j];
    }
#pragma unroll
    for (int m = 0; m < 4; ++m) {
#pragma unroll
        for (int r = 0; r < 4; ++r) {
            int i = i0 + wr * 64 + m * 16 + (lane >> 4) * 4 + r;
            float sqi = sq[i]; int lbi = lab[i];
#pragma unroll
            for (int n = 0; n < 4; ++n) {
                float d2 = sqi + sqj[n] - 2.f * acc[m][n][r];
                float dist = sqrtf(fmaxf(d2, 0.f));
                float v = (lbi == lbj[n]) ? dist : fmaxf(0.f, GAMMA_F - dist);
                v = (i < jj[n]) ? v : 0.f;
                lsum += v;
            }
        }
    }
#pragma unroll
    for (int o = 32; o > 0; o >>= 1) lsum += __shfl_xor(lsum, o);
    if (lane == 0) red[w] = lsum;
    __syncthreads();
    if (t == 0) {
        float s = 0.f;
#pragma unroll
        for (int q = 0; q < 8; ++q) s += red[q];
        psum[blockIdx.x] = 2.f * s;
    }
}

// ---------------- Kernel 4: tree-reduce partials + combine
__global__ __launch_bounds__(256) void finalize_kernel(
    const float* __restrict__ csum, const float* __restrict__ psum,
    float* __restrict__ out)
{
    __shared__ float rce[4], rcon[4];
    int w = threadIdx.x >> 6, lane = threadIdx.x & 63;
    float s_ce = 0.f, s_con = 0.f;
    for (int i = threadIdx.x; i < NBLK_CE; i += 256) s_ce += csum[i];
    for (int i = threadIdx.x; i < NBLK_CON; i += 256) s_con += psum[i];
#pragma unroll
    for (int o = 32; o > 0; o >>= 1) {
        s_ce += __shfl_xor(s_ce, o);
        s_con += __shfl_xor(s_con, o);
    }
    if (lane == 0) { rce[w] = s_ce; rcon[w] = s_con; }
    __syncthreads();
    if (threadIdx.x == 0) {
        float ce = rce[0] + rce[1] + rce[2] + rce[3];
        float con = rcon[0] + rcon[1] + rcon[2] + rcon[3];
        out[0] = (1.f - LAM_F) * (ce / (float)B_ROWS) + LAM_F * con;
    }
}

extern "C" void kernel_launch(void* const* d_in, const int* in_sizes, int n_in,
                              void* d_out, int out_size, void* d_ws, size_t ws_size,
                              hipStream_t stream) {
    const float* pooled = (const float*)d_in[0];
    const float* tgt    = (const float*)d_in[1];
    const int*   labels = (const int*)d_in[2];
    const float* W      = (const float*)d_in[3];
    const float* bias   = (const float*)d_in[4];
    float* out = (float*)d_out;

    float* csum = (float*)d_ws;                                   // 2048 f32
    float* psum = (float*)((char*)d_ws + 8192);                   // 1056 f32
    float* sq   = (float*)((char*)d_ws + 20480);                  // 8192 f32
    unsigned short* Ebf = (unsigned short*)((char*)d_ws + 53248); // bf16 E, 12.6 MB

    prep_kernel<<<B_ROWS / 4, 256, 0, stream>>>(tgt, Ebf, sq);
    ce_kernel<<<NBLK_CE, 256, 0, stream>>>(pooled, W, bias, labels, out, csum);
    con_kernel<<<NBLK_CON, 512, 0, stream>>>(Ebf, sq, labels, psum);
    finalize_kernel<<<1, 256, 0, stream>>>(csum, psum, out);
}